// Round 1
// baseline (619.874 us; speedup 1.0000x reference)
//
#include <hip/hip_runtime.h>
#include <cstdint>
#include <cstddef>

typedef __bf16 bf16x8 __attribute__((ext_vector_type(8)));
typedef float f32x4 __attribute__((ext_vector_type(4)));
typedef unsigned short u16x8 __attribute__((ext_vector_type(8)));

#define VT_LD 56  // padded j-stride of V^T rows: 56*2B = 112B (16B-aligned rows)

__device__ __forceinline__ unsigned short f2bf(float f) {
  unsigned int u = __builtin_bit_cast(unsigned int, f);
  u += 0x7FFFu + ((u >> 16) & 1u);   // RNE
  return (unsigned short)(u >> 16);
}

__device__ __forceinline__ void gload_lds16(const void* g, void* l) {
  __builtin_amdgcn_global_load_lds((const __attribute__((address_space(1))) void*)g,
                                   (__attribute__((address_space(3))) void*)l, 16, 0, 0);
}

// ---------------- kernel 0a: qkv_w fp32 -> bf16 ----------------
__global__ void conv_w_k(const float* __restrict__ w, unsigned short* __restrict__ wb) {
  int i = blockIdx.x * 256 + threadIdx.x;   // grid sized exactly: 1536*512 = 3072*256
  wb[i] = f2bf(w[i]);
}

// ---------------- kernel 0b: bias table [16][49][49] fp32 ----------------
__global__ void build_bias_k(const float* __restrict__ rpb, float* __restrict__ biasT) {
  int idx = blockIdx.x * 256 + threadIdx.x;
  if (idx >= 16 * 2401) return;
  int h = idx / 2401;
  int rem = idx - h * 2401;
  int i = rem / 49, j = rem - (rem / 49) * 49;
  int r1 = i / 7, c1 = i - r1 * 7;
  int r2 = j / 7, c2 = j - r2 * 7;
  int ri = (r1 - r2 + 6) * 13 + (c1 - c2 + 6);
  biasT[idx] = rpb[ri * 16 + h];
}

// ---------------- kernel 1: QKV projection GEMM ----------------
// out[m][n] = sum_k x[m][k] * w[n][k] + b[n]; M=100352, N=1536, K=512
// scatter: n -> (s,h,d); s=0: QS=(val*scale), s=1: K, s=2: VT (transposed)
__global__ __launch_bounds__(256, 2) void qkv_gemm_k(
    const float* __restrict__ x, const float* __restrict__ qkv_b,
    const unsigned short* __restrict__ wb,
    unsigned short* __restrict__ qs, unsigned short* __restrict__ kk,
    unsigned short* __restrict__ vt)
{
  __shared__ unsigned short Ab[128 * 32];
  __shared__ unsigned short Bb[128 * 32];

  int bid = blockIdx.x;
  // XCD swizzle (9408 % 8 == 0 -> bijective)
  int sw = (bid & 7) * 1176 + (bid >> 3);
  int mt = sw / 12, nt = sw - mt * 12;   // N fast: 12 blocks share one A panel
  long m0 = (long)mt * 128;
  int  n0 = nt * 128;

  int t = threadIdx.x;
  int lane = t & 63, wv = t >> 6;
  int g = lane >> 4, q = lane & 15;
  int wrow = wv >> 1, wcol = wv & 1;

  f32x4 acc[4][4] = {};

  // A staging: thread t loads 16 fp32 of row (t>>1), converts to bf16
  int arow = t >> 1, acol = (t & 1) * 16;
  const float* ag = x + (m0 + arow) * 512 + acol;
  unsigned short* al = Ab + arow * 32 + acol;

  // B staging via global_load_lds: LDS linear byte offset == 16*t
  const unsigned short* bg0 = wb + (size_t)(n0 + (t >> 2)) * 512 + (t & 3) * 8;
  const unsigned short* bg1 = bg0 + 64 * 512;
  unsigned short* bl0 = Bb + wv * 512;          // wave-uniform base (wv*1024 B)
  unsigned short* bl1 = Bb + 2048 + wv * 512;   // +4096 B

  for (int kt = 0; kt < 16; ++kt) {
    int k0 = kt * 32;
    gload_lds16(bg0 + k0, bl0);
    gload_lds16(bg1 + k0, bl1);
    float4 a0 = *(const float4*)(ag + k0);
    float4 a1 = *(const float4*)(ag + k0 + 4);
    float4 a2 = *(const float4*)(ag + k0 + 8);
    float4 a3 = *(const float4*)(ag + k0 + 12);
    u16x8 p0, p1;
    p0[0]=f2bf(a0.x); p0[1]=f2bf(a0.y); p0[2]=f2bf(a0.z); p0[3]=f2bf(a0.w);
    p0[4]=f2bf(a1.x); p0[5]=f2bf(a1.y); p0[6]=f2bf(a1.z); p0[7]=f2bf(a1.w);
    p1[0]=f2bf(a2.x); p1[1]=f2bf(a2.y); p1[2]=f2bf(a2.z); p1[3]=f2bf(a2.w);
    p1[4]=f2bf(a3.x); p1[5]=f2bf(a3.y); p1[6]=f2bf(a3.z); p1[7]=f2bf(a3.w);
    *(u16x8*)al = p0;
    *(u16x8*)(al + 8) = p1;
    __syncthreads();   // drains vmcnt (global_load_lds) + lgkmcnt

    const unsigned short* ab = Ab + (wrow * 64 + q) * 32 + 8 * g;
    const unsigned short* bb = Bb + (wcol * 64 + q) * 32 + 8 * g;
    bf16x8 af[4], bfr[4];
    #pragma unroll
    for (int i2 = 0; i2 < 4; ++i2) af[i2]  = *(const bf16x8*)(ab + i2 * 512);
    #pragma unroll
    for (int i2 = 0; i2 < 4; ++i2) bfr[i2] = *(const bf16x8*)(bb + i2 * 512);
    #pragma unroll
    for (int i2 = 0; i2 < 4; ++i2)
      #pragma unroll
      for (int j2 = 0; j2 < 4; ++j2)
        acc[i2][j2] = __builtin_amdgcn_mfma_f32_16x16x32_bf16(af[i2], bfr[j2], acc[i2][j2], 0, 0, 0);
    __syncthreads();
  }

  // epilogue: bias add + scatter to QS / K / VT
  #pragma unroll
  for (int j2 = 0; j2 < 4; ++j2) {
    int gn = n0 + wcol * 64 + j2 * 16 + q;
    float bias = qkv_b[gn];
    int s = gn >> 9;           // uniform per (j2): 0=q,1=k,2=v
    int h = (gn >> 5) & 15;
    int d = gn & 31;
    #pragma unroll
    for (int i2 = 0; i2 < 4; ++i2) {
      #pragma unroll
      for (int r = 0; r < 4; ++r) {
        int gm = (int)m0 + wrow * 64 + i2 * 16 + 4 * g + r;
        int b = gm / 49;
        int i = gm - b * 49;
        float v = acc[i2][j2][r] + bias;
        int bh = b * 16 + h;
        if (s == 0) {
          qs[(size_t)(bh * 49 + i) * 32 + d] = f2bf(v * 0.17677669529663687f);
        } else if (s == 1) {
          kk[(size_t)(bh * 49 + i) * 32 + d] = f2bf(v);
        } else {
          vt[((size_t)bh * 32 + d) * VT_LD + i] = f2bf(v);
        }
      }
    }
  }
}

// ---------------- kernel 2: fused window attention ----------------
__global__ __launch_bounds__(256, 2) void win_attn_k(
    const unsigned short* __restrict__ qs, const unsigned short* __restrict__ kk,
    const unsigned short* __restrict__ vt, const float* __restrict__ biasT,
    const float* __restrict__ mask, float* __restrict__ out)
{
  __shared__ float mlds[49 * 49];
  __shared__ unsigned short plds[4][64 * 72];   // per-wave P, +8 pad (2-way banks)

  int b = blockIdx.x;
  int t = threadIdx.x;
  int lane = t & 63, wv = t >> 6;
  int g = lane >> 4, q = lane & 15;

  const float* msrc = mask + (size_t)(b & 63) * 2401;
  for (int idx = t; idx < 2401; idx += 256) mlds[idx] = msrc[idx];
  __syncthreads();

  unsigned short* pl = plds[wv];

  for (int hh = 0; hh < 4; ++hh) {
    int h = wv * 4 + hh;
    const unsigned short* qh = qs + (size_t)(b * 16 + h) * (49 * 32);
    const unsigned short* kh = kk + (size_t)(b * 16 + h) * (49 * 32);
    const unsigned short* vh = vt + (size_t)(b * 16 + h) * (32 * VT_LD);
    const float* bhp = biasT + h * 2401;

    // S = (Q*scale) @ K^T   [64x64 padded, valid 49x49]
    bf16x8 aq[4], bk[4];
    #pragma unroll
    for (int it = 0; it < 4; ++it) {
      int row = it * 16 + q; row = row > 48 ? 48 : row;   // clamp pad rows
      aq[it] = *(const bf16x8*)(qh + row * 32 + 8 * g);
    }
    #pragma unroll
    for (int jt = 0; jt < 4; ++jt) {
      int row = jt * 16 + q; row = row > 48 ? 48 : row;
      bk[jt] = *(const bf16x8*)(kh + row * 32 + 8 * g);
    }
    f32x4 zero = {0.f, 0.f, 0.f, 0.f};
    f32x4 st[4][4];
    #pragma unroll
    for (int it = 0; it < 4; ++it)
      #pragma unroll
      for (int jt = 0; jt < 4; ++jt)
        st[it][jt] = __builtin_amdgcn_mfma_f32_16x16x32_bf16(aq[it], bk[jt], zero, 0, 0, 0);

    // bias + mask + row softmax (rows spread: i = it*16 + 4g + r; cols j = jt*16 + q)
    float rinv[4][4];
    #pragma unroll
    for (int it = 0; it < 4; ++it) {
      #pragma unroll
      for (int r = 0; r < 4; ++r) {
        int i = it * 16 + 4 * g + r;
        int ic = i > 48 ? 48 : i;
        float vj[4];
        #pragma unroll
        for (int jt = 0; jt < 4; ++jt) {
          int j = jt * 16 + q;
          float val;
          if (j < 49) val = st[it][jt][r] + bhp[ic * 49 + j] + mlds[ic * 49 + j];
          else        val = -__builtin_inff();
          vj[jt] = val;
        }
        float mx = fmaxf(fmaxf(vj[0], vj[1]), fmaxf(vj[2], vj[3]));
        #pragma unroll
        for (int off = 1; off < 16; off <<= 1) mx = fmaxf(mx, __shfl_xor(mx, off));
        float sm = 0.f;
        #pragma unroll
        for (int jt = 0; jt < 4; ++jt) {
          float p = __expf(vj[jt] - mx);   // j>=49 -> exp(-inf)=0
          st[it][jt][r] = p;
          sm += p;
        }
        #pragma unroll
        for (int off = 1; off < 16; off <<= 1) sm += __shfl_xor(sm, off);
        rinv[it][r] = 1.0f / sm;           // sm >= 1
      }
    }

    // P -> LDS (bf16, unnormalized)
    #pragma unroll
    for (int it = 0; it < 4; ++it)
      #pragma unroll
      for (int jt = 0; jt < 4; ++jt)
        #pragma unroll
        for (int r = 0; r < 4; ++r) {
          int i = it * 16 + 4 * g + r;
          int j = jt * 16 + q;
          pl[i * 72 + j] = f2bf(st[it][jt][r]);
        }
    __syncthreads();

    // O = P @ V  via VT (B frag: k=j contiguous along VT rows)
    f32x4 oacc[4][2] = {};
    #pragma unroll
    for (int ktt = 0; ktt < 2; ++ktt) {
      bf16x8 pa[4], bv[2];
      #pragma unroll
      for (int it = 0; it < 4; ++it)
        pa[it] = *(const bf16x8*)(pl + (it * 16 + q) * 72 + ktt * 32 + 8 * g);
      #pragma unroll
      for (int dt = 0; dt < 2; ++dt)
        bv[dt] = *(const bf16x8*)(vh + (dt * 16 + q) * VT_LD + ktt * 32 + 8 * g);
      #pragma unroll
      for (int it = 0; it < 4; ++it)
        #pragma unroll
        for (int dt = 0; dt < 2; ++dt)
          oacc[it][dt] = __builtin_amdgcn_mfma_f32_16x16x32_bf16(pa[it], bv[dt], oacc[it][dt], 0, 0, 0);
    }

    // store fp32 output [b*49+i][h*32+d]
    #pragma unroll
    for (int it = 0; it < 4; ++it) {
      #pragma unroll
      for (int dt = 0; dt < 2; ++dt) {
        #pragma unroll
        for (int r = 0; r < 4; ++r) {
          int i = it * 16 + 4 * g + r;
          if (i < 49) {
            int d = dt * 16 + q;
            out[(size_t)(b * 49 + i) * 512 + h * 32 + d] = oacc[it][dt][r] * rinv[it][r];
          }
        }
      }
    }
    __syncthreads();   // keep waves aligned before reusing per-wave P region
  }
}

// ---------------- launcher ----------------
extern "C" void kernel_launch(void* const* d_in, const int* in_sizes, int n_in,
                              void* d_out, int out_size, void* d_ws, size_t ws_size,
                              hipStream_t stream) {
  const float* x     = (const float*)d_in[0];
  const float* mask  = (const float*)d_in[1];
  const float* qkv_w = (const float*)d_in[2];
  const float* qkv_b = (const float*)d_in[3];
  const float* rpb   = (const float*)d_in[4];
  float* out = (float*)d_out;

  // workspace layout (bytes)
  const size_t QS_OFF   = 0;                         // 2048*16*49*32*2 = 102,760,448
  const size_t KK_OFF   = 102760448;
  const size_t VT_OFF   = 205520896;                 // 2048*16*32*56*2 = 117,440,512
  const size_t BIAS_OFF = 322961408;                 // 16*49*49*4     = 153,664
  const size_t WB_OFF   = 323115072;                 // 1536*512*2     = 1,572,864
  const size_t NEED     = 324687936;
  if (ws_size < NEED) return;                        // ws too small: recognizable failure

  char* ws = (char*)d_ws;
  unsigned short* qsb   = (unsigned short*)(ws + QS_OFF);
  unsigned short* kkb   = (unsigned short*)(ws + KK_OFF);
  unsigned short* vtb   = (unsigned short*)(ws + VT_OFF);
  float*          biasT = (float*)(ws + BIAS_OFF);
  unsigned short* wb    = (unsigned short*)(ws + WB_OFF);

  conv_w_k<<<3072, 256, 0, stream>>>(qkv_w, wb);
  build_bias_k<<<151, 256, 0, stream>>>(rpb, biasT);
  qkv_gemm_k<<<9408, 256, 0, stream>>>(x, qkv_b, wb, qsb, kkb, vtb);
  win_attn_k<<<2048, 256, 0, stream>>>(qsb, kkb, vtb, biasT, mask, out);
}

// Round 2
// 568.224 us; speedup vs baseline: 1.0909x; 1.0909x over previous
//
#include <hip/hip_runtime.h>
#include <cstdint>
#include <cstddef>

typedef __bf16 bf16x8 __attribute__((ext_vector_type(8)));
typedef float f32x4 __attribute__((ext_vector_type(4)));
typedef unsigned short u16x8 __attribute__((ext_vector_type(8)));

#define VT_LD 56  // padded j-stride of V^T rows: 56*2B = 112B (16B-aligned rows)

__device__ __forceinline__ unsigned short f2bf(float f) {
  unsigned int u = __builtin_bit_cast(unsigned int, f);
  u += 0x7FFFu + ((u >> 16) & 1u);   // RNE
  return (unsigned short)(u >> 16);
}

__device__ __forceinline__ void gload_lds16(const void* g, void* l) {
  __builtin_amdgcn_global_load_lds((const __attribute__((address_space(1))) void*)g,
                                   (__attribute__((address_space(3))) void*)l, 16, 0, 0);
}

// ---------------- kernel 0: generic fp32 -> bf16 (vec8, grid-stride) ----------------
__global__ void conv_f2b_k(const float* __restrict__ src, unsigned short* __restrict__ dst, long n8) {
  long i = (long)blockIdx.x * blockDim.x + threadIdx.x;
  long stride = (long)gridDim.x * blockDim.x;
  for (; i < n8; i += stride) {
    float4 a = *(const float4*)(src + i * 8);
    float4 b = *(const float4*)(src + i * 8 + 4);
    u16x8 p;
    p[0]=f2bf(a.x); p[1]=f2bf(a.y); p[2]=f2bf(a.z); p[3]=f2bf(a.w);
    p[4]=f2bf(b.x); p[5]=f2bf(b.y); p[6]=f2bf(b.z); p[7]=f2bf(b.w);
    *(u16x8*)(dst + i * 8) = p;
  }
}

// ---------------- kernel 0b: bias table [16][49][49] fp32 ----------------
__global__ void build_bias_k(const float* __restrict__ rpb, float* __restrict__ biasT) {
  int idx = blockIdx.x * 256 + threadIdx.x;
  if (idx >= 16 * 2401) return;
  int h = idx / 2401;
  int rem = idx - h * 2401;
  int i = rem / 49, j = rem - (rem / 49) * 49;
  int r1 = i / 7, c1 = i - r1 * 7;
  int r2 = j / 7, c2 = j - r2 * 7;
  int ri = (r1 - r2 + 6) * 13 + (c1 - c2 + 6);
  biasT[idx] = rpb[ri * 16 + h];
}

// ---------------- kernel 1: QKV projection GEMM (pure bf16, m97 structure) ----------------
// out[m][n] = sum_k xb[m][k] * wb[n][k] + b[n]; M=100352, N=1536, K=512
// scatter: n -> (s,h,d); s=0: QS=(val*scale), s=1: K, s=2: VT (transposed)
__global__ __launch_bounds__(256, 3) void qkv_gemm_k(
    const unsigned short* __restrict__ xb, const float* __restrict__ qkv_b,
    const unsigned short* __restrict__ wb,
    unsigned short* __restrict__ qs, unsigned short* __restrict__ kk,
    unsigned short* __restrict__ vt)
{
  __shared__ unsigned short Ab[128 * 32];
  __shared__ unsigned short Bb[128 * 32];

  int bid = blockIdx.x;
  // XCD swizzle (9408 % 8 == 0 -> bijective)
  int sw = (bid & 7) * 1176 + (bid >> 3);
  int mt = sw / 12, nt = sw - mt * 12;   // N fast: 12 blocks share one A panel
  long m0 = (long)mt * 128;
  int  n0 = nt * 128;

  int t = threadIdx.x;
  int lane = t & 63, wv = t >> 6;
  int g = lane >> 4, q = lane & 15;
  int wrow = wv >> 1, wcol = wv & 1;

  f32x4 acc[4][4] = {};

  // A staging via global_load_lds: thread t covers row t>>2, col-chunk (t&3)*8
  const unsigned short* ag0 = xb + (m0 + (t >> 2)) * 512 + (t & 3) * 8;
  const unsigned short* ag1 = ag0 + 64 * 512;
  unsigned short* al0 = Ab + wv * 512;           // wave-uniform base (wv*1024 B)
  unsigned short* al1 = Ab + 2048 + wv * 512;
  // B staging identical pattern
  const unsigned short* bg0 = wb + (size_t)(n0 + (t >> 2)) * 512 + (t & 3) * 8;
  const unsigned short* bg1 = bg0 + 64 * 512;
  unsigned short* bl0 = Bb + wv * 512;
  unsigned short* bl1 = Bb + 2048 + wv * 512;

  const unsigned short* ab = Ab + (wrow * 64 + q) * 32 + 8 * g;
  const unsigned short* bb = Bb + (wcol * 64 + q) * 32 + 8 * g;

  for (int kt = 0; kt < 16; ++kt) {
    int k0 = kt * 32;
    gload_lds16(ag0 + k0, al0);
    gload_lds16(ag1 + k0, al1);
    gload_lds16(bg0 + k0, bl0);
    gload_lds16(bg1 + k0, bl1);
    __syncthreads();   // drains vmcnt (global_load_lds)

    bf16x8 af[4], bfr[4];
    #pragma unroll
    for (int i2 = 0; i2 < 4; ++i2) af[i2]  = *(const bf16x8*)(ab + i2 * 512);
    #pragma unroll
    for (int i2 = 0; i2 < 4; ++i2) bfr[i2] = *(const bf16x8*)(bb + i2 * 512);
    #pragma unroll
    for (int i2 = 0; i2 < 4; ++i2)
      #pragma unroll
      for (int j2 = 0; j2 < 4; ++j2)
        acc[i2][j2] = __builtin_amdgcn_mfma_f32_16x16x32_bf16(af[i2], bfr[j2], acc[i2][j2], 0, 0, 0);
    __syncthreads();
  }

  // epilogue: bias add + scatter to QS / K / VT
  #pragma unroll
  for (int j2 = 0; j2 < 4; ++j2) {
    int gn = n0 + wcol * 64 + j2 * 16 + q;
    float bias = qkv_b[gn];
    int s = gn >> 9;           // uniform per (j2): 0=q,1=k,2=v
    int h = (gn >> 5) & 15;
    int d = gn & 31;
    #pragma unroll
    for (int i2 = 0; i2 < 4; ++i2) {
      #pragma unroll
      for (int r = 0; r < 4; ++r) {
        int gm = (int)m0 + wrow * 64 + i2 * 16 + 4 * g + r;
        int b = gm / 49;
        int i = gm - b * 49;
        float v = acc[i2][j2][r] + bias;
        int bh = b * 16 + h;
        if (s == 0) {
          qs[(size_t)(bh * 49 + i) * 32 + d] = f2bf(v * 0.17677669529663687f);
        } else if (s == 1) {
          kk[(size_t)(bh * 49 + i) * 32 + d] = f2bf(v);
        } else {
          vt[((size_t)bh * 32 + d) * VT_LD + i] = f2bf(v);
        }
      }
    }
  }
}

// ---------------- kernel 2: fused window attention ----------------
__global__ __launch_bounds__(256, 2) void win_attn_k(
    const unsigned short* __restrict__ qs, const unsigned short* __restrict__ kk,
    const unsigned short* __restrict__ vt, const float* __restrict__ biasT,
    const float* __restrict__ mask, float* __restrict__ out)
{
  __shared__ float mlds[49 * 49];
  __shared__ unsigned short plds[4][64 * 72];   // per-wave P, +8 pad (2-way banks)

  int b = blockIdx.x;
  int t = threadIdx.x;
  int lane = t & 63, wv = t >> 6;
  int g = lane >> 4, q = lane & 15;

  const float* msrc = mask + (size_t)(b & 63) * 2401;
  for (int idx = t; idx < 2401; idx += 256) mlds[idx] = msrc[idx];
  __syncthreads();

  unsigned short* pl = plds[wv];

  for (int hh = 0; hh < 4; ++hh) {
    int h = wv * 4 + hh;
    const unsigned short* qh = qs + (size_t)(b * 16 + h) * (49 * 32);
    const unsigned short* kh = kk + (size_t)(b * 16 + h) * (49 * 32);
    const unsigned short* vh = vt + (size_t)(b * 16 + h) * (32 * VT_LD);
    const float* bhp = biasT + h * 2401;

    // S = (Q*scale) @ K^T   [64x64 padded, valid 49x49]
    bf16x8 aq[4], bk[4];
    #pragma unroll
    for (int it = 0; it < 4; ++it) {
      int row = it * 16 + q; row = row > 48 ? 48 : row;   // clamp pad rows
      aq[it] = *(const bf16x8*)(qh + row * 32 + 8 * g);
    }
    #pragma unroll
    for (int jt = 0; jt < 4; ++jt) {
      int row = jt * 16 + q; row = row > 48 ? 48 : row;
      bk[jt] = *(const bf16x8*)(kh + row * 32 + 8 * g);
    }
    f32x4 zero = {0.f, 0.f, 0.f, 0.f};
    f32x4 st[4][4];
    #pragma unroll
    for (int it = 0; it < 4; ++it)
      #pragma unroll
      for (int jt = 0; jt < 4; ++jt)
        st[it][jt] = __builtin_amdgcn_mfma_f32_16x16x32_bf16(aq[it], bk[jt], zero, 0, 0, 0);

    // bias + mask + row softmax (rows spread: i = it*16 + 4g + r; cols j = jt*16 + q)
    float rinv[4][4];
    #pragma unroll
    for (int it = 0; it < 4; ++it) {
      #pragma unroll
      for (int r = 0; r < 4; ++r) {
        int i = it * 16 + 4 * g + r;
        int ic = i > 48 ? 48 : i;
        float vj[4];
        #pragma unroll
        for (int jt = 0; jt < 4; ++jt) {
          int j = jt * 16 + q;
          float val;
          if (j < 49) val = st[it][jt][r] + bhp[ic * 49 + j] + mlds[ic * 49 + j];
          else        val = -__builtin_inff();
          vj[jt] = val;
        }
        float mx = fmaxf(fmaxf(vj[0], vj[1]), fmaxf(vj[2], vj[3]));
        #pragma unroll
        for (int off = 1; off < 16; off <<= 1) mx = fmaxf(mx, __shfl_xor(mx, off));
        float sm = 0.f;
        #pragma unroll
        for (int jt = 0; jt < 4; ++jt) {
          float p = __expf(vj[jt] - mx);   // j>=49 -> exp(-inf)=0
          st[it][jt][r] = p;
          sm += p;
        }
        #pragma unroll
        for (int off = 1; off < 16; off <<= 1) sm += __shfl_xor(sm, off);
        rinv[it][r] = 1.0f / sm;           // sm >= 1
      }
    }

    // P -> LDS (bf16, unnormalized). Same-wave region: no barrier needed
    // (DS pipe is in-order per wave; compiler inserts lgkmcnt before reads).
    #pragma unroll
    for (int it = 0; it < 4; ++it)
      #pragma unroll
      for (int jt = 0; jt < 4; ++jt)
        #pragma unroll
        for (int r = 0; r < 4; ++r) {
          int i = it * 16 + 4 * g + r;
          int j = jt * 16 + q;
          pl[i * 72 + j] = f2bf(st[it][jt][r]);
        }

    // O = P @ V  via VT (B frag: k=j contiguous along VT rows)
    f32x4 oacc[4][2] = {};
    #pragma unroll
    for (int ktt = 0; ktt < 2; ++ktt) {
      bf16x8 pa[4], bv[2];
      #pragma unroll
      for (int it = 0; it < 4; ++it)
        pa[it] = *(const bf16x8*)(pl + (it * 16 + q) * 72 + ktt * 32 + 8 * g);
      #pragma unroll
      for (int dt = 0; dt < 2; ++dt)
        bv[dt] = *(const bf16x8*)(vh + (dt * 16 + q) * VT_LD + ktt * 32 + 8 * g);
      #pragma unroll
      for (int it = 0; it < 4; ++it)
        #pragma unroll
        for (int dt = 0; dt < 2; ++dt)
          oacc[it][dt] = __builtin_amdgcn_mfma_f32_16x16x32_bf16(pa[it], bv[dt], oacc[it][dt], 0, 0, 0);
    }

    // store fp32 output [b*49+i][h*32+d]
    #pragma unroll
    for (int it = 0; it < 4; ++it) {
      #pragma unroll
      for (int dt = 0; dt < 2; ++dt) {
        #pragma unroll
        for (int r = 0; r < 4; ++r) {
          int i = it * 16 + 4 * g + r;
          if (i < 49) {
            int d = dt * 16 + q;
            out[(size_t)(b * 49 + i) * 512 + h * 32 + d] = oacc[it][dt][r] * rinv[it][r];
          }
        }
      }
    }
  }
}

// ---------------- launcher ----------------
extern "C" void kernel_launch(void* const* d_in, const int* in_sizes, int n_in,
                              void* d_out, int out_size, void* d_ws, size_t ws_size,
                              hipStream_t stream) {
  const float* x     = (const float*)d_in[0];
  const float* mask  = (const float*)d_in[1];
  const float* qkv_w = (const float*)d_in[2];
  const float* qkv_b = (const float*)d_in[3];
  const float* rpb   = (const float*)d_in[4];
  float* out = (float*)d_out;

  // workspace layout (bytes)
  const size_t QS_OFF   = 0;                         // 2048*16*49*32*2 = 102,760,448
  const size_t KK_OFF   = 102760448;
  const size_t VT_OFF   = 205520896;                 // 2048*16*32*56*2 = 117,440,512
  const size_t BIAS_OFF = 322961408;                 // 16*49*49*4     = 153,664
  const size_t WB_OFF   = 323115072;                 // 1536*512*2     = 1,572,864
  const size_t NEED     = 324687936;
  if (ws_size < NEED) return;                        // ws too small: recognizable failure

  char* ws = (char*)d_ws;
  unsigned short* qsb   = (unsigned short*)(ws + QS_OFF);
  unsigned short* kkb   = (unsigned short*)(ws + KK_OFF);
  unsigned short* vtb   = (unsigned short*)(ws + VT_OFF);
  float*          biasT = (float*)(ws + BIAS_OFF);
  unsigned short* wb    = (unsigned short*)(ws + WB_OFF);

  // xb (bf16 x, 103 MB) lives in d_out (205 MB fp32) — dead until win_attn
  // fully overwrites it. Deterministic: rewritten every call.
  unsigned short* xb = (unsigned short*)d_out;

  conv_f2b_k<<<2048, 256, 0, stream>>>(x, xb, 6422528);        // 100352*512/8
  conv_f2b_k<<<512, 256, 0, stream>>>(qkv_w, wb, 98304);       // 1536*512/8
  build_bias_k<<<151, 256, 0, stream>>>(rpb, biasT);
  qkv_gemm_k<<<9408, 256, 0, stream>>>(xb, qkv_b, wb, qsb, kkb, vtb);
  win_attn_k<<<2048, 256, 0, stream>>>(qsb, kkb, vtb, biasT, mask, out);
}

// Round 3
// 510.354 us; speedup vs baseline: 1.2146x; 1.1134x over previous
//
#include <hip/hip_runtime.h>
#include <cstdint>
#include <cstddef>

typedef __bf16 bf16x8 __attribute__((ext_vector_type(8)));
typedef float f32x4 __attribute__((ext_vector_type(4)));
typedef unsigned short u16x8 __attribute__((ext_vector_type(8)));

#define VT_LD 56  // padded j-stride of V^T rows
#define LDE 144   // epilogue LDS row stride (shorts): 288B -> 8*g bank offset, 2-way free

__device__ __forceinline__ unsigned short f2bf(float f) {
  unsigned int u = __builtin_bit_cast(unsigned int, f);
  u += 0x7FFFu + ((u >> 16) & 1u);   // RNE
  return (unsigned short)(u >> 16);
}

__device__ __forceinline__ void gload_lds16(const void* g, void* l) {
  __builtin_amdgcn_global_load_lds((const __attribute__((address_space(1))) void*)g,
                                   (__attribute__((address_space(3))) void*)l, 16, 0, 0);
}

// ---------------- kernel 0: generic fp32 -> bf16 (vec8, grid-stride) ----------------
__global__ void conv_f2b_k(const float* __restrict__ src, unsigned short* __restrict__ dst, long n8) {
  long i = (long)blockIdx.x * blockDim.x + threadIdx.x;
  long stride = (long)gridDim.x * blockDim.x;
  for (; i < n8; i += stride) {
    float4 a = *(const float4*)(src + i * 8);
    float4 b = *(const float4*)(src + i * 8 + 4);
    u16x8 p;
    p[0]=f2bf(a.x); p[1]=f2bf(a.y); p[2]=f2bf(a.z); p[3]=f2bf(a.w);
    p[4]=f2bf(b.x); p[5]=f2bf(b.y); p[6]=f2bf(b.z); p[7]=f2bf(b.w);
    *(u16x8*)(dst + i * 8) = p;
  }
}

// ---------------- kernel 0b: bias table [16][49][49] fp32 ----------------
__global__ void build_bias_k(const float* __restrict__ rpb, float* __restrict__ biasT) {
  int idx = blockIdx.x * 256 + threadIdx.x;
  if (idx >= 16 * 2401) return;
  int h = idx / 2401;
  int rem = idx - h * 2401;
  int i = rem / 49, j = rem - (rem / 49) * 49;
  int r1 = i / 7, c1 = i - r1 * 7;
  int r2 = j / 7, c2 = j - r2 * 7;
  int ri = (r1 - r2 + 6) * 13 + (c1 - c2 + 6);
  biasT[idx] = rpb[ri * 16 + h];
}

// ---------------- kernel 1: QKV projection GEMM (m97 K-loop + cheap epilogue) ----------------
// out[m][n] = sum_k xb[m][k] * wb[n][k] + b[n]; M=100352, N=1536, K=512
// s = n0>>9 uniform per block: 0 -> QS(*scale), 1 -> K, 2 -> VT(transposed)
__global__ __launch_bounds__(256, 3) void qkv_gemm_k(
    const unsigned short* __restrict__ xb, const float* __restrict__ qkv_b,
    const unsigned short* __restrict__ wb,
    unsigned short* __restrict__ qs, unsigned short* __restrict__ kk,
    unsigned short* __restrict__ vt)
{
  // [0,4096) A-tile, [4096,8192) B-tile (shorts); epilogue aliases [0,18432)
  __shared__ __align__(16) unsigned short smem[18432];
  unsigned short* Ab = smem;
  unsigned short* Bb = smem + 4096;

  int bid = blockIdx.x;
  // XCD swizzle (9408 % 8 == 0 -> bijective)
  int sw = (bid & 7) * 1176 + (bid >> 3);
  int mt = sw / 12, nt = sw - mt * 12;   // N fast: 12 blocks share one A panel
  long m0 = (long)mt * 128;
  int  n0 = nt * 128;
  int  s  = n0 >> 9;                     // block-uniform output kind

  int t = threadIdx.x;
  int lane = t & 63, wv = t >> 6;
  int g = lane >> 4, q = lane & 15;
  int wrow = wv >> 1, wcol = wv & 1;

  f32x4 acc[4][4] = {};

  // Staging: linear LDS dest (t*16B), INVERSE-swizzled global source chunk
  // (rule #21: data for LDS slot (row, c) is global chunk c ^ ((row>>1)&3)).
  int schunk = (t & 3) ^ ((t >> 3) & 3);
  const unsigned short* ag0 = xb + (m0 + (t >> 2)) * 512 + schunk * 8;
  const unsigned short* ag1 = ag0 + 64 * 512;
  unsigned short* al0 = Ab + wv * 512;          // wave-uniform base
  unsigned short* al1 = Ab + 2048 + wv * 512;
  const unsigned short* bg0 = wb + (size_t)(n0 + (t >> 2)) * 512 + schunk * 8;
  const unsigned short* bg1 = bg0 + 64 * 512;
  unsigned short* bl0 = Bb + wv * 512;
  unsigned short* bl1 = Bb + 2048 + wv * 512;

  // Swizzled frag-read offset: for rows == q (mod 16), sigma = (q>>1)&3 (per-lane const)
  int roff = (8 * g) ^ (((q >> 1) & 3) << 3);
  const unsigned short* ab = Ab + (wrow * 64 + q) * 32 + roff;
  const unsigned short* bb = Bb + (wcol * 64 + q) * 32 + roff;

  for (int kt = 0; kt < 16; ++kt) {
    int k0 = kt * 32;
    gload_lds16(ag0 + k0, al0);
    gload_lds16(ag1 + k0, al1);
    gload_lds16(bg0 + k0, bl0);
    gload_lds16(bg1 + k0, bl1);
    __syncthreads();   // drains vmcnt (global_load_lds)

    bf16x8 af[4], bfr[4];
    #pragma unroll
    for (int i2 = 0; i2 < 4; ++i2) af[i2]  = *(const bf16x8*)(ab + i2 * 512);
    #pragma unroll
    for (int i2 = 0; i2 < 4; ++i2) bfr[i2] = *(const bf16x8*)(bb + i2 * 512);
    #pragma unroll
    for (int i2 = 0; i2 < 4; ++i2)
      #pragma unroll
      for (int j2 = 0; j2 < 4; ++j2)
        acc[i2][j2] = __builtin_amdgcn_mfma_f32_16x16x32_bf16(af[i2], bfr[j2], acc[i2][j2], 0, 0, 0);
    __syncthreads();
  }

  // ---- epilogue ----
  int   nl[4];
  float bias[4];
  #pragma unroll
  for (int j2 = 0; j2 < 4; ++j2) {
    nl[j2] = wcol * 64 + j2 * 16 + q;
    bias[j2] = qkv_b[n0 + nl[j2]];
  }

  if (s < 2) {
    // Q/K: restage tile through LDS, vectorized 16B stores
    float sc = (s == 0) ? 0.17677669529663687f : 1.0f;
    #pragma unroll
    for (int i2 = 0; i2 < 4; ++i2) {
      #pragma unroll
      for (int r = 0; r < 4; ++r) {
        int ml = wrow * 64 + i2 * 16 + 4 * g + r;
        #pragma unroll
        for (int j2 = 0; j2 < 4; ++j2)
          smem[ml * LDE + nl[j2]] = f2bf((acc[i2][j2][r] + bias[j2]) * sc);
      }
    }
    __syncthreads();
    unsigned short* dst = (s == 0) ? qs : kk;
    int c8 = (t & 15) * 8;
    int d0 = c8 & 31;
    int h  = ((n0 + c8) >> 5) & 15;
    #pragma unroll
    for (int p = 0; p < 8; ++p) {
      int row = p * 16 + (t >> 4);
      unsigned int gm = (unsigned int)m0 + row;
      unsigned int b  = gm / 49;
      unsigned int i  = gm - b * 49;
      u16x8 val = *(const u16x8*)(smem + row * LDE + c8);
      *(u16x8*)(dst + ((size_t)(b * 16 + h) * 49 + i) * 32 + d0) = val;
    }
  } else {
    // V: thread's 4 r-values are consecutive i in VT -> packed dword stores
    #pragma unroll
    for (int j2 = 0; j2 < 4; ++j2) {
      int d = nl[j2] & 31;
      int h = ((n0 + nl[j2]) >> 5) & 15;
      #pragma unroll
      for (int i2 = 0; i2 < 4; ++i2) {
        unsigned int gm0 = (unsigned int)m0 + wrow * 64 + i2 * 16 + 4 * g;
        unsigned int b0 = gm0 / 49;
        unsigned int i0 = gm0 - b0 * 49;
        unsigned short hv[4];
        #pragma unroll
        for (int r = 0; r < 4; ++r) hv[r] = f2bf(acc[i2][j2][r] + bias[j2]);
        if (i0 <= 45) {
          unsigned short* base = vt + ((size_t)(b0 * 16 + h) * 32 + d) * VT_LD;
          if ((i0 & 1) == 0) {
            *(unsigned int*)(base + i0)     = (unsigned int)hv[0] | ((unsigned int)hv[1] << 16);
            *(unsigned int*)(base + i0 + 2) = (unsigned int)hv[2] | ((unsigned int)hv[3] << 16);
          } else {
            base[i0] = hv[0];
            *(unsigned int*)(base + i0 + 1) = (unsigned int)hv[1] | ((unsigned int)hv[2] << 16);
            base[i0 + 3] = hv[3];
          }
        } else {
          #pragma unroll
          for (int r = 0; r < 4; ++r) {
            unsigned int gm = gm0 + r;
            unsigned int b = gm / 49;
            unsigned int i = gm - b * 49;
            vt[((size_t)(b * 16 + h) * 32 + d) * VT_LD + i] = hv[r];
          }
        }
      }
    }
  }
}

// ---------------- kernel 2: fused window attention ----------------
__global__ __launch_bounds__(256, 2) void win_attn_k(
    const unsigned short* __restrict__ qs, const unsigned short* __restrict__ kk,
    const unsigned short* __restrict__ vt, const float* __restrict__ biasT,
    const float* __restrict__ mask, float* __restrict__ out)
{
  __shared__ float mlds[49 * 49];
  __shared__ unsigned short plds[4][64 * 72];   // per-wave P, +8 pad

  int b = blockIdx.x;
  int t = threadIdx.x;
  int lane = t & 63, wv = t >> 6;
  int g = lane >> 4, q = lane & 15;

  const float* msrc = mask + (size_t)(b & 63) * 2401;
  for (int idx = t; idx < 2401; idx += 256) mlds[idx] = msrc[idx];
  __syncthreads();

  unsigned short* pl = plds[wv];

  for (int hh = 0; hh < 4; ++hh) {
    int h = wv * 4 + hh;
    const unsigned short* qh = qs + (size_t)(b * 16 + h) * (49 * 32);
    const unsigned short* kh = kk + (size_t)(b * 16 + h) * (49 * 32);
    const unsigned short* vh = vt + (size_t)(b * 16 + h) * (32 * VT_LD);
    const float* bhp = biasT + h * 2401;

    // S = (Q*scale) @ K^T   [64x64 padded, valid 49x49]
    bf16x8 aq[4], bk[4];
    #pragma unroll
    for (int it = 0; it < 4; ++it) {
      int row = it * 16 + q; row = row > 48 ? 48 : row;   // clamp pad rows
      aq[it] = *(const bf16x8*)(qh + row * 32 + 8 * g);
    }
    #pragma unroll
    for (int jt = 0; jt < 4; ++jt) {
      int row = jt * 16 + q; row = row > 48 ? 48 : row;
      bk[jt] = *(const bf16x8*)(kh + row * 32 + 8 * g);
    }
    f32x4 zero = {0.f, 0.f, 0.f, 0.f};
    f32x4 st[4][4];
    __builtin_amdgcn_s_setprio(1);
    #pragma unroll
    for (int it = 0; it < 4; ++it)
      #pragma unroll
      for (int jt = 0; jt < 4; ++jt)
        st[it][jt] = __builtin_amdgcn_mfma_f32_16x16x32_bf16(aq[it], bk[jt], zero, 0, 0, 0);
    __builtin_amdgcn_s_setprio(0);

    // bias + mask + row softmax (rows: i = it*16 + 4g + r; cols j = jt*16 + q)
    float rinv[4][4];
    #pragma unroll
    for (int it = 0; it < 4; ++it) {
      #pragma unroll
      for (int r = 0; r < 4; ++r) {
        int i = it * 16 + 4 * g + r;
        int ic = i > 48 ? 48 : i;
        float vj[4];
        #pragma unroll
        for (int jt = 0; jt < 4; ++jt) {
          int j = jt * 16 + q;
          float val;
          if (j < 49) val = st[it][jt][r] + bhp[ic * 49 + j] + mlds[ic * 49 + j];
          else        val = -__builtin_inff();
          vj[jt] = val;
        }
        float mx = fmaxf(fmaxf(vj[0], vj[1]), fmaxf(vj[2], vj[3]));
        #pragma unroll
        for (int off = 1; off < 16; off <<= 1) mx = fmaxf(mx, __shfl_xor(mx, off));
        float sm = 0.f;
        #pragma unroll
        for (int jt = 0; jt < 4; ++jt) {
          float p = __expf(vj[jt] - mx);   // j>=49 -> exp(-inf)=0
          st[it][jt][r] = p;
          sm += p;
        }
        #pragma unroll
        for (int off = 1; off < 16; off <<= 1) sm += __shfl_xor(sm, off);
        rinv[it][r] = 1.0f / sm;           // sm >= 1
      }
    }

    // P -> LDS (bf16, unnormalized). Same-wave region: no barrier needed.
    #pragma unroll
    for (int it = 0; it < 4; ++it)
      #pragma unroll
      for (int jt = 0; jt < 4; ++jt)
        #pragma unroll
        for (int r = 0; r < 4; ++r) {
          int i = it * 16 + 4 * g + r;
          int j = jt * 16 + q;
          pl[i * 72 + j] = f2bf(st[it][jt][r]);
        }

    // O = P @ V  via VT (B frag: k=j contiguous along VT rows)
    f32x4 oacc[4][2] = {};
    #pragma unroll
    for (int ktt = 0; ktt < 2; ++ktt) {
      bf16x8 pa[4], bv[2];
      #pragma unroll
      for (int it = 0; it < 4; ++it)
        pa[it] = *(const bf16x8*)(pl + (it * 16 + q) * 72 + ktt * 32 + 8 * g);
      #pragma unroll
      for (int dt = 0; dt < 2; ++dt)
        bv[dt] = *(const bf16x8*)(vh + (dt * 16 + q) * VT_LD + ktt * 32 + 8 * g);
      __builtin_amdgcn_s_setprio(1);
      #pragma unroll
      for (int it = 0; it < 4; ++it)
        #pragma unroll
        for (int dt = 0; dt < 2; ++dt)
          oacc[it][dt] = __builtin_amdgcn_mfma_f32_16x16x32_bf16(pa[it], bv[dt], oacc[it][dt], 0, 0, 0);
      __builtin_amdgcn_s_setprio(0);
    }

    // store fp32 output [b*49+i][h*32+d]
    #pragma unroll
    for (int it = 0; it < 4; ++it) {
      #pragma unroll
      for (int dt = 0; dt < 2; ++dt) {
        #pragma unroll
        for (int r = 0; r < 4; ++r) {
          int i = it * 16 + 4 * g + r;
          if (i < 49) {
            int d = dt * 16 + q;
            out[(size_t)(b * 49 + i) * 512 + h * 32 + d] = oacc[it][dt][r] * rinv[it][r];
          }
        }
      }
    }
  }
}

// ---------------- launcher ----------------
extern "C" void kernel_launch(void* const* d_in, const int* in_sizes, int n_in,
                              void* d_out, int out_size, void* d_ws, size_t ws_size,
                              hipStream_t stream) {
  const float* x     = (const float*)d_in[0];
  const float* mask  = (const float*)d_in[1];
  const float* qkv_w = (const float*)d_in[2];
  const float* qkv_b = (const float*)d_in[3];
  const float* rpb   = (const float*)d_in[4];
  float* out = (float*)d_out;

  // workspace layout (bytes)
  const size_t QS_OFF   = 0;                         // 2048*16*49*32*2 = 102,760,448
  const size_t KK_OFF   = 102760448;
  const size_t VT_OFF   = 205520896;                 // 2048*16*32*56*2 = 117,440,512
  const size_t BIAS_OFF = 322961408;                 // 16*49*49*4     = 153,664
  const size_t WB_OFF   = 323115072;                 // 1536*512*2     = 1,572,864
  const size_t NEED     = 324687936;
  if (ws_size < NEED) return;

  char* ws = (char*)d_ws;
  unsigned short* qsb   = (unsigned short*)(ws + QS_OFF);
  unsigned short* kkb   = (unsigned short*)(ws + KK_OFF);
  unsigned short* vtb   = (unsigned short*)(ws + VT_OFF);
  float*          biasT = (float*)(ws + BIAS_OFF);
  unsigned short* wb    = (unsigned short*)(ws + WB_OFF);

  // xb (bf16 x, 103 MB) lives in d_out (205 MB fp32) — dead until win_attn
  // fully overwrites it. Deterministic: rewritten every call.
  unsigned short* xb = (unsigned short*)d_out;

  conv_f2b_k<<<2048, 256, 0, stream>>>(x, xb, 6422528);        // 100352*512/8
  conv_f2b_k<<<512, 256, 0, stream>>>(qkv_w, wb, 98304);       // 1536*512/8
  build_bias_k<<<151, 256, 0, stream>>>(rpb, biasT);
  qkv_gemm_k<<<9408, 256, 0, stream>>>(xb, qkv_b, wb, qsb, kkb, vtb);
  win_attn_k<<<2048, 256, 0, stream>>>(qsb, kkb, vtb, biasT, mask, out);
}